// Round 7
// baseline (259.094 us; speedup 1.0000x reference)
//
#include <hip/hip_runtime.h>
#include <math.h>

// z (16,64,64,64) f32 (b,c,h,w), codebook (1024,64) f32. Out: z_q + loss.
#define NB 16
#define NC 64
#define NH 64
#define NW 64
#define NE 1024
#define HW (NH * NW)              // 4096 = 1<<12
#define NTOT (NB * NC * NH * NW)  // 4194304
#define NPIX (NB * NH * NW)       // 65536 pixels (rows)

#define ROWS 128                  // pixels per block
#define NBLK (NPIX / ROWS)        // 512 blocks

typedef short bf16x8 __attribute__((ext_vector_type(8)));
typedef float f32x4  __attribute__((ext_vector_type(4)));

// XOR swizzle within a 128-byte row (A-tile LDS only).
__device__ __forceinline__ int swz(int row, int byteoff) {
    return (byteoff ^ ((row & 7) << 4));
}

// fp32 -> bf16 bits, round-to-nearest-even.
__device__ __forceinline__ unsigned short bf16bits(float f) {
    union { float f; unsigned u; } cv;
    cv.f = f;
    const unsigned u = cv.u;
    return (unsigned short)((u + 0x7FFFu + ((u >> 16) & 1u)) >> 16);
}

// ---------------- prep: bf16 codebook + (-0.5*||e||^2) into ws ----------------
__global__ void vq_prep_kernel(const float* __restrict__ cb,
                               short* __restrict__ cbw,
                               float* __restrict__ ncbn) {
    const int gid = blockIdx.x * blockDim.x + threadIdx.x;  // 0..4095
    const int row = gid >> 2;
    const int q   = gid & 3;
    const float4* __restrict__ src = (const float4*)(cb + ((size_t)row << 6) + q * 16);
    float ssq = 0.f;
    bf16x8 pk0, pk1;
    {
        const float4 a = src[0], b = src[1];
        ssq += a.x * a.x + a.y * a.y + a.z * a.z + a.w * a.w
             + b.x * b.x + b.y * b.y + b.z * b.z + b.w * b.w;
        pk0[0] = (short)bf16bits(a.x); pk0[1] = (short)bf16bits(a.y);
        pk0[2] = (short)bf16bits(a.z); pk0[3] = (short)bf16bits(a.w);
        pk0[4] = (short)bf16bits(b.x); pk0[5] = (short)bf16bits(b.y);
        pk0[6] = (short)bf16bits(b.z); pk0[7] = (short)bf16bits(b.w);
    }
    {
        const float4 a = src[2], b = src[3];
        ssq += a.x * a.x + a.y * a.y + a.z * a.z + a.w * a.w
             + b.x * b.x + b.y * b.y + b.z * b.z + b.w * b.w;
        pk1[0] = (short)bf16bits(a.x); pk1[1] = (short)bf16bits(a.y);
        pk1[2] = (short)bf16bits(a.z); pk1[3] = (short)bf16bits(a.w);
        pk1[4] = (short)bf16bits(b.x); pk1[5] = (short)bf16bits(b.y);
        pk1[6] = (short)bf16bits(b.z); pk1[7] = (short)bf16bits(b.w);
    }
    bf16x8* dst = (bf16x8*)(cbw + ((size_t)row << 6) + q * 16);
    dst[0] = pk0;
    dst[1] = pk1;
    ssq += __shfl_xor(ssq, 1, 64);
    ssq += __shfl_xor(ssq, 2, 64);
    if (q == 0) ncbn[row] = -0.5f * ssq;
}

// ---------------- ablation/main kernel family ----------------
// V=1: stage z + A-frags only (sink)            V=2: +inner sweep (sink)
// V=3: +shuffle argmin (sink)                   V=4: +epilogue, partial->pbuf
// V=5: == R6 exactly (epilogue z re-read, atomicAdd loss)
// V=6: improved real: z kept in regs, partial->pbuf (no atomic)
template <int V>
__global__ __launch_bounds__(256, 2)
void vq_abl_kernel(const float* __restrict__ z,
                   const short* __restrict__ cbw,
                   const float* __restrict__ ncbn,
                   const float* __restrict__ cb,
                   float* __restrict__ out,
                   float* __restrict__ loss,
                   float* __restrict__ pbuf) {
    __shared__ __align__(16) short zt[ROWS * 64];  // 16 KB, swizzled
    __shared__ float ncbn_s[NE];                   // 4 KB
    __shared__ int   rowi[ROWS];
    __shared__ float swsum[4];

    const int tid  = threadIdx.x;
    const int wave = tid >> 6;
    const int lane = tid & 63;
    const int bid  = blockIdx.x;

    ((float4*)ncbn_s)[tid] = ((const float4*)ncbn)[tid];

    // ---- phase 1: stage z tile; V6 keeps the fp32 values in registers ----
    const int r     = tid & 127;
    const int chalf = tid >> 7;
    const int P     = bid * ROWS + r;
    const int b     = P >> 12;
    const int rem   = P & 4095;
    const size_t zb = ((size_t)b << 18) + rem;

    float zfr[32];  // static-indexed only (rule #20)
    #pragma unroll
    for (int q = 0; q < 4; ++q) {
        #pragma unroll
        for (int jj = 0; jj < 8; ++jj) {
            const int c = chalf * 32 + q * 8 + jj;
            zfr[q * 8 + jj] = z[zb + ((size_t)c << 12)];
        }
        bf16x8 pk;
        #pragma unroll
        for (int jj = 0; jj < 8; ++jj)
            pk[jj] = (short)bf16bits(zfr[q * 8 + jj]);
        const int boff = (chalf * 32 + q * 8) * 2;
        *(bf16x8*)((char*)zt + r * 128 + swz(r, boff)) = pk;
    }
    __syncthreads();

    // ---- A fragments: lane l -> row (l&15), k = (l>>4)*8 + j ----
    bf16x8 af[2][2];
    #pragma unroll
    for (int m = 0; m < 2; ++m) {
        const int rr = wave * 32 + m * 16 + (lane & 15);
        #pragma unroll
        for (int k0 = 0; k0 < 2; ++k0) {
            const int boff = k0 * 64 + (lane >> 4) * 16;
            af[m][k0] = *(const bf16x8*)((const char*)zt + rr * 128 + swz(rr, boff));
        }
    }

    if constexpr (V == 1) {
        int s = 0;
        #pragma unroll
        for (int m = 0; m < 2; ++m)
            #pragma unroll
            for (int k0 = 0; k0 < 2; ++k0)
                #pragma unroll
                for (int j = 0; j < 8; ++j) s += af[m][k0][j];
        out[P + chalf * NPIX] = (float)s + ncbn_s[tid & 1023];
        return;
    }

    // ---- inner sweep: 64 n-tiles, no barriers ----
    float maxv[2][4];
    int   maxi[2][4];
    #pragma unroll
    for (int m = 0; m < 2; ++m)
        #pragma unroll
        for (int j = 0; j < 4; ++j) { maxv[m][j] = -INFINITY; maxi[m][j] = 0; }

    const short* __restrict__ bptr = cbw + ((lane >> 4) << 3);
    #pragma unroll 4
    for (int nt = 0; nt < NE / 16; ++nt) {
        const int el = nt * 16 + (lane & 15);
        const bf16x8 b0 = *(const bf16x8*)(bptr + el * 64);
        const bf16x8 b1 = *(const bf16x8*)(bptr + el * 64 + 32);
        const float  ncb = ncbn_s[el];
        #pragma unroll
        for (int m = 0; m < 2; ++m) {
            f32x4 acc = {ncb, ncb, ncb, ncb};
            acc = __builtin_amdgcn_mfma_f32_16x16x32_bf16(af[m][0], b0, acc, 0, 0, 0);
            acc = __builtin_amdgcn_mfma_f32_16x16x32_bf16(af[m][1], b1, acc, 0, 0, 0);
            #pragma unroll
            for (int j = 0; j < 4; ++j) {
                if (acc[j] > maxv[m][j]) { maxv[m][j] = acc[j]; maxi[m][j] = el; }
            }
        }
    }

    if constexpr (V == 2) {
        float fs = 0.f;
        #pragma unroll
        for (int m = 0; m < 2; ++m)
            #pragma unroll
            for (int j = 0; j < 4; ++j) fs += maxv[m][j] + (float)maxi[m][j];
        out[P + chalf * NPIX] = fs;
        return;
    }

    // ---- cross-lane argmax -> rowi ----
    #pragma unroll
    for (int m = 0; m < 2; ++m) {
        #pragma unroll
        for (int j = 0; j < 4; ++j) {
            float v = maxv[m][j];
            int   i = maxi[m][j];
            #pragma unroll
            for (int s = 1; s < 16; s <<= 1) {
                const float ov = __shfl_xor(v, s, 64);
                const int   oi = __shfl_xor(i, s, 64);
                if (ov > v || (ov == v && oi < i)) { v = ov; i = oi; }
            }
            if ((lane & 15) == 0) {
                const int rr = wave * 32 + m * 16 + (lane >> 4) * 4 + j;
                rowi[rr] = i;
            }
        }
    }
    __syncthreads();

    if constexpr (V == 3) {
        out[P + chalf * NPIX] = (float)rowi[tid & 127];
        return;
    }

    // ---- epilogue ----
    float lsum = 0.f;
    {
        const int mi = rowi[r];
        const float4* __restrict__ qrow = (const float4*)(cb + ((size_t)mi << 6));
        #pragma unroll
        for (int q = 0; q < 8; ++q) {
            const float4 q4 = qrow[chalf * 8 + q];
            const int c = chalf * 32 + q * 4;
            float z0, z1, z2, z3;
            if constexpr (V == 6) {
                z0 = zfr[q * 4 + 0]; z1 = zfr[q * 4 + 1];
                z2 = zfr[q * 4 + 2]; z3 = zfr[q * 4 + 3];
            } else {
                z0 = z[zb + ((size_t)(c + 0) << 12)];
                z1 = z[zb + ((size_t)(c + 1) << 12)];
                z2 = z[zb + ((size_t)(c + 2) << 12)];
                z3 = z[zb + ((size_t)(c + 3) << 12)];
            }
            out[zb + ((size_t)(c + 0) << 12)] = q4.x;
            out[zb + ((size_t)(c + 1) << 12)] = q4.y;
            out[zb + ((size_t)(c + 2) << 12)] = q4.z;
            out[zb + ((size_t)(c + 3) << 12)] = q4.w;
            const float d0 = q4.x - z0, d1 = q4.y - z1;
            const float d2 = q4.z - z2, d3 = q4.w - z3;
            lsum += d0 * d0 + d1 * d1 + d2 * d2 + d3 * d3;
        }
    }

    // wait — V6 epilogue channel mapping: zfr[q*4..] holds channels
    // chalf*32 + (q*4..q*4+3) only when q<8 maps c=chalf*32+q*4 ✓ (zfr index
    // is c - chalf*32 = q*4+i ✓).

    #pragma unroll
    for (int off = 32; off > 0; off >>= 1)
        lsum += __shfl_xor(lsum, off, 64);
    if (lane == 0) swsum[wave] = lsum;
    __syncthreads();
    if (tid == 0) {
        const float s = (swsum[0] + swsum[1]) + (swsum[2] + swsum[3]);
        if constexpr (V == 5) {
            atomicAdd(loss, s * (1.25f / (float)NTOT));
        } else {
            pbuf[bid] = s;  // V4 / V6: per-block partial, no atomic
        }
    }
}

// ---------------- final: reduce 512 partials -> loss ----------------
__global__ void vq_reduce_kernel(const float* __restrict__ pbuf,
                                 float* __restrict__ loss) {
    __shared__ float sw[8];
    const int tid = threadIdx.x;  // 512
    float v = pbuf[tid];
    #pragma unroll
    for (int off = 32; off > 0; off >>= 1)
        v += __shfl_xor(v, off, 64);
    if ((tid & 63) == 0) sw[tid >> 6] = v;
    __syncthreads();
    if (tid == 0) {
        float s = 0.f;
        #pragma unroll
        for (int i = 0; i < 8; ++i) s += sw[i];
        loss[0] = s * (1.25f / (float)NTOT);
    }
}

extern "C" void kernel_launch(void* const* d_in, const int* in_sizes, int n_in,
                              void* d_out, int out_size, void* d_ws, size_t ws_size,
                              hipStream_t stream) {
    const float* z  = (const float*)d_in[0];
    const float* cb = (const float*)d_in[1];
    float* out  = (float*)d_out;
    float* loss = out + (out_size - 1);

    short* cbw  = (short*)d_ws;                        // [1024][64] bf16 (128 KB)
    float* ncbn = (float*)(cbw + NE * NC);             // [1024] f32 (4 KB)
    float* pbuf = ncbn + NE;                           // [512] f32 partials (2 KB)

    vq_prep_kernel<<<dim3(16), dim3(256), 0, stream>>>(cb, cbw, ncbn);

    // Diagnostic ablation dispatches (rocprof per-dispatch rows are the
    // readout). They only scribble inside out[0..NTOT-1] / pbuf, which the
    // real V6 + reduce fully overwrite afterwards.
    vq_abl_kernel<1><<<dim3(NBLK), dim3(256), 0, stream>>>(z, cbw, ncbn, cb, out, loss, pbuf);
    vq_abl_kernel<2><<<dim3(NBLK), dim3(256), 0, stream>>>(z, cbw, ncbn, cb, out, loss, pbuf);
    vq_abl_kernel<3><<<dim3(NBLK), dim3(256), 0, stream>>>(z, cbw, ncbn, cb, out, loss, pbuf);
    vq_abl_kernel<4><<<dim3(NBLK), dim3(256), 0, stream>>>(z, cbw, ncbn, cb, out, loss, pbuf);
    vq_abl_kernel<5><<<dim3(NBLK), dim3(256), 0, stream>>>(z, cbw, ncbn, cb, out, loss, pbuf);

    // Real path: improved kernel + partial reduce (no same-address atomics).
    vq_abl_kernel<6><<<dim3(NBLK), dim3(256), 0, stream>>>(z, cbw, ncbn, cb, out, loss, pbuf);
    vq_reduce_kernel<<<dim3(1), dim3(512), 0, stream>>>(pbuf, loss);
}

// Round 8
// 135.001 us; speedup vs baseline: 1.9192x; 1.9192x over previous
//
#include <hip/hip_runtime.h>
#include <math.h>

// z (16,64,64,64) f32 (b,c,h,w), codebook (1024,64) f32. Out: z_q + loss.
#define NB 16
#define NC 64
#define NH 64
#define NW 64
#define NE 1024
#define HW (NH * NW)              // 4096 = 1<<12
#define NTOT (NB * NC * NH * NW)  // 4194304
#define NPIX (NB * NH * NW)       // 65536 pixels (rows)

#define ROWS 64                   // pixels per block (1 M-tile of 16 per wave)
#define NBLK (NPIX / ROWS)        // 1024 blocks -> 4 blocks/CU, 16 waves/CU

typedef short bf16x8 __attribute__((ext_vector_type(8)));
typedef float f32x4  __attribute__((ext_vector_type(4)));

// XOR swizzle within a 128-byte row (A-tile LDS only).
__device__ __forceinline__ int swz(int row, int byteoff) {
    return (byteoff ^ ((row & 7) << 4));
}

// fp32 -> bf16 bits, round-to-nearest-even.
__device__ __forceinline__ unsigned short bf16bits(float f) {
    union { float f; unsigned u; } cv;
    cv.f = f;
    const unsigned u = cv.u;
    return (unsigned short)((u + 0x7FFFu + ((u >> 16) & 1u)) >> 16);
}

// ---------------- prep: bf16 codebook + (-0.5*||e||^2) into ws ----------------
__global__ void vq_prep_kernel(const float* __restrict__ cb,
                               short* __restrict__ cbw,
                               float* __restrict__ ncbn) {
    const int gid = blockIdx.x * blockDim.x + threadIdx.x;  // 0..4095
    const int row = gid >> 2;
    const int q   = gid & 3;
    const float4* __restrict__ src = (const float4*)(cb + ((size_t)row << 6) + q * 16);
    float ssq = 0.f;
    bf16x8 pk0, pk1;
    {
        const float4 a = src[0], b = src[1];
        ssq += a.x * a.x + a.y * a.y + a.z * a.z + a.w * a.w
             + b.x * b.x + b.y * b.y + b.z * b.z + b.w * b.w;
        pk0[0] = (short)bf16bits(a.x); pk0[1] = (short)bf16bits(a.y);
        pk0[2] = (short)bf16bits(a.z); pk0[3] = (short)bf16bits(a.w);
        pk0[4] = (short)bf16bits(b.x); pk0[5] = (short)bf16bits(b.y);
        pk0[6] = (short)bf16bits(b.z); pk0[7] = (short)bf16bits(b.w);
    }
    {
        const float4 a = src[2], b = src[3];
        ssq += a.x * a.x + a.y * a.y + a.z * a.z + a.w * a.w
             + b.x * b.x + b.y * b.y + b.z * b.z + b.w * b.w;
        pk1[0] = (short)bf16bits(a.x); pk1[1] = (short)bf16bits(a.y);
        pk1[2] = (short)bf16bits(a.z); pk1[3] = (short)bf16bits(a.w);
        pk1[4] = (short)bf16bits(b.x); pk1[5] = (short)bf16bits(b.y);
        pk1[6] = (short)bf16bits(b.z); pk1[7] = (short)bf16bits(b.w);
    }
    bf16x8* dst = (bf16x8*)(cbw + ((size_t)row << 6) + q * 16);
    dst[0] = pk0;
    dst[1] = pk1;
    ssq += __shfl_xor(ssq, 1, 64);
    ssq += __shfl_xor(ssq, 2, 64);
    if (q == 0) ncbn[row] = -0.5f * ssq;
}

// ---------------- main: 16 waves/CU, 1 M-tile per wave ----------------
// 1024 blocks x 256 thr (4 waves). Wave w owns rows w*16..w*16+15.
// A (z tile) in LDS (bf16, swizzled); B straight from L2-resident bf16
// codebook; -0.5||e||^2 added AFTER the MFMA chain (ds_read overlaps MFMA).
__launch_bounds__(256, 4)
__global__ void vq_main_kernel(const float* __restrict__ z,
                               const short* __restrict__ cbw,
                               const float* __restrict__ ncbn,
                               const float* __restrict__ cb,
                               float* __restrict__ out,
                               float* __restrict__ pbuf) {
    __shared__ __align__(16) short zt[ROWS * 64];  // 8 KB, swizzled
    __shared__ float ncbn_s[NE];                   // 4 KB
    __shared__ int   rowi[ROWS];
    __shared__ float swsum[4];

    const int tid  = threadIdx.x;
    const int wave = tid >> 6;
    const int lane = tid & 63;
    const int bid  = blockIdx.x;

    // stage ncbn (1024 floats) via 256 x float4
    ((float4*)ncbn_s)[tid] = ((const float4*)ncbn)[tid];

    // ---- stage z tile: thread -> row (tid&63), channel quarter (tid>>6) ----
    const int r   = tid & 63;
    const int cq  = tid >> 6;                 // 16 channels: cq*16..cq*16+15
    const int P   = bid * ROWS + r;
    const int b   = P >> 12;
    const int rem = P & 4095;
    const size_t zb = ((size_t)b << 18) + rem;
    #pragma unroll
    for (int q = 0; q < 2; ++q) {
        bf16x8 pk;
        #pragma unroll
        for (int jj = 0; jj < 8; ++jj) {
            const int c = cq * 16 + q * 8 + jj;
            pk[jj] = (short)bf16bits(z[zb + ((size_t)c << 12)]);
        }
        const int boff = (cq * 16 + q * 8) * 2;
        *(bf16x8*)((char*)zt + r * 128 + swz(r, boff)) = pk;
    }
    __syncthreads();

    // ---- A fragments: lane l -> row wave*16+(l&15), k = (l>>4)*8 + j ----
    bf16x8 af0, af1;
    {
        const int rr = wave * 16 + (lane & 15);
        af0 = *(const bf16x8*)((const char*)zt + rr * 128 + swz(rr, 0  + (lane >> 4) * 16));
        af1 = *(const bf16x8*)((const char*)zt + rr * 128 + swz(rr, 64 + (lane >> 4) * 16));
    }

    float maxv[4];
    int   maxi[4];
    #pragma unroll
    for (int j = 0; j < 4; ++j) { maxv[j] = -INFINITY; maxi[j] = 0; }

    // ---- sweep all 1024 entries: 64 independent n-tiles, no barriers ----
    const short* __restrict__ bptr = cbw + ((lane >> 4) << 3);
    #pragma unroll 4
    for (int nt = 0; nt < NE / 16; ++nt) {
        const int el = nt * 16 + (lane & 15);     // entry (= B col) = global idx
        const bf16x8 b0 = *(const bf16x8*)(bptr + el * 64);
        const bf16x8 b1 = *(const bf16x8*)(bptr + el * 64 + 32);
        const float  ncb = ncbn_s[el];            // overlaps MFMA chain below
        f32x4 acc = {0.f, 0.f, 0.f, 0.f};
        acc = __builtin_amdgcn_mfma_f32_16x16x32_bf16(af0, b0, acc, 0, 0, 0);
        acc = __builtin_amdgcn_mfma_f32_16x16x32_bf16(af1, b1, acc, 0, 0, 0);
        #pragma unroll
        for (int j = 0; j < 4; ++j) {
            const float sc = acc[j] + ncb;
            if (sc > maxv[j]) { maxv[j] = sc; maxi[j] = el; }
        }
    }

    // ---- cross-lane argmax over the 16 cols per row ----
    // element (j, lane): row = wave*16 + (lane>>4)*4 + j.
    #pragma unroll
    for (int j = 0; j < 4; ++j) {
        float v = maxv[j];
        int   i = maxi[j];
        #pragma unroll
        for (int s = 1; s < 16; s <<= 1) {
            const float ov = __shfl_xor(v, s, 64);
            const int   oi = __shfl_xor(i, s, 64);
            if (ov > v || (ov == v && oi < i)) { v = ov; i = oi; }
        }
        if ((lane & 15) == 0) {
            const int rr = wave * 16 + (lane >> 4) * 4 + j;
            rowi[rr] = i;
        }
    }
    __syncthreads();

    // ---- epilogue: gather fp32 codebook row, store out, loss ----
    float lsum = 0.f;
    {
        const int mi = rowi[r];
        const float4* __restrict__ qrow = (const float4*)(cb + ((size_t)mi << 6) + cq * 16);
        #pragma unroll
        for (int q = 0; q < 4; ++q) {
            const float4 q4 = qrow[q];
            const int c = cq * 16 + q * 4;
            const float z0 = z[zb + ((size_t)(c + 0) << 12)];
            const float z1 = z[zb + ((size_t)(c + 1) << 12)];
            const float z2 = z[zb + ((size_t)(c + 2) << 12)];
            const float z3 = z[zb + ((size_t)(c + 3) << 12)];
            out[zb + ((size_t)(c + 0) << 12)] = q4.x;
            out[zb + ((size_t)(c + 1) << 12)] = q4.y;
            out[zb + ((size_t)(c + 2) << 12)] = q4.z;
            out[zb + ((size_t)(c + 3) << 12)] = q4.w;
            const float d0 = q4.x - z0, d1 = q4.y - z1;
            const float d2 = q4.z - z2, d3 = q4.w - z3;
            lsum += d0 * d0 + d1 * d1 + d2 * d2 + d3 * d3;
        }
    }

    #pragma unroll
    for (int off = 32; off > 0; off >>= 1)
        lsum += __shfl_xor(lsum, off, 64);
    if (lane == 0) swsum[wave] = lsum;
    __syncthreads();
    if (tid == 0) {
        pbuf[bid] = (swsum[0] + swsum[1]) + (swsum[2] + swsum[3]);
    }
}

// ---------------- final: reduce 1024 partials -> loss ----------------
__global__ void vq_reduce_kernel(const float* __restrict__ pbuf,
                                 float* __restrict__ loss) {
    __shared__ float sw[4];
    const int tid = threadIdx.x;  // 256
    const float4 v4 = ((const float4*)pbuf)[tid];
    float v = (v4.x + v4.y) + (v4.z + v4.w);
    #pragma unroll
    for (int off = 32; off > 0; off >>= 1)
        v += __shfl_xor(v, off, 64);
    if ((tid & 63) == 0) sw[tid >> 6] = v;
    __syncthreads();
    if (tid == 0) {
        const float s = (sw[0] + sw[1]) + (sw[2] + sw[3]);
        loss[0] = s * (1.25f / (float)NTOT);
    }
}

extern "C" void kernel_launch(void* const* d_in, const int* in_sizes, int n_in,
                              void* d_out, int out_size, void* d_ws, size_t ws_size,
                              hipStream_t stream) {
    const float* z  = (const float*)d_in[0];
    const float* cb = (const float*)d_in[1];
    float* out  = (float*)d_out;
    float* loss = out + (out_size - 1);

    short* cbw  = (short*)d_ws;                        // [1024][64] bf16 (128 KB)
    float* ncbn = (float*)(cbw + NE * NC);             // [1024] f32 (4 KB)
    float* pbuf = ncbn + NE;                           // [1024] f32 partials (4 KB)

    vq_prep_kernel<<<dim3(16), dim3(256), 0, stream>>>(cb, cbw, ncbn);
    vq_main_kernel<<<dim3(NBLK), dim3(256), 0, stream>>>(z, cbw, ncbn, cb, out, pbuf);
    vq_reduce_kernel<<<dim3(1), dim3(256), 0, stream>>>(pbuf, loss);
}

// Round 9
// 100.040 us; speedup vs baseline: 2.5899x; 1.3495x over previous
//
#include <hip/hip_runtime.h>
#include <math.h>

// z (16,64,64,64) f32 (b,c,h,w), codebook (1024,64) f32. Out: z_q + loss.
#define NB 16
#define NC 64
#define NH 64
#define NW 64
#define NE 1024
#define HW (NH * NW)              // 4096 = 1<<12
#define NTOT (NB * NC * NH * NW)  // 4194304
#define NPIX (NB * NH * NW)       // 65536 pixels (rows)

#define ROWS 128                  // pixels per block
#define NBLK (NPIX / ROWS)        // 512 blocks (R8: bigger grid = more B-traffic = slower)

typedef short bf16x8 __attribute__((ext_vector_type(8)));
typedef float f32x4  __attribute__((ext_vector_type(4)));

// XOR swizzle within a 128-byte row (A-tile LDS only).
__device__ __forceinline__ int swz(int row, int byteoff) {
    return (byteoff ^ ((row & 7) << 4));
}

// fp32 -> bf16 bits, round-to-nearest-even.
__device__ __forceinline__ unsigned short bf16bits(float f) {
    union { float f; unsigned u; } cv;
    cv.f = f;
    const unsigned u = cv.u;
    return (unsigned short)((u + 0x7FFFu + ((u >> 16) & 1u)) >> 16);
}

// ---------------- prep: FRAGMENT-ORDER bf16 codebook + (-0.5||e||^2) ----------------
// cbw layout (16-B units): idx = nt*128 + half*64 + kgrp*16 + col
//   entry e = nt*16 + col; k-chunk = half*4 + kgrp (8 bf16 each).
// Main-loop lane l then loads b0/b1 at base + l*16: 64 lanes unit-stride
// contiguous 1 KB per instruction (dense, fully coalesced).
__global__ void vq_prep_kernel(const float* __restrict__ cb,
                               short* __restrict__ cbw,
                               float* __restrict__ ncbn) {
    const int gid = blockIdx.x * blockDim.x + threadIdx.x;  // 0..4095
    const int e   = gid >> 2;
    const int q   = gid & 3;      // 16-channel quarter: k = q*16 .. q*16+15
    const float4* __restrict__ src = (const float4*)(cb + ((size_t)e << 6) + q * 16);
    float ssq = 0.f;
    bf16x8 pk0, pk1;
    {
        const float4 a = src[0], b = src[1];
        ssq += a.x * a.x + a.y * a.y + a.z * a.z + a.w * a.w
             + b.x * b.x + b.y * b.y + b.z * b.z + b.w * b.w;
        pk0[0] = (short)bf16bits(a.x); pk0[1] = (short)bf16bits(a.y);
        pk0[2] = (short)bf16bits(a.z); pk0[3] = (short)bf16bits(a.w);
        pk0[4] = (short)bf16bits(b.x); pk0[5] = (short)bf16bits(b.y);
        pk0[6] = (short)bf16bits(b.z); pk0[7] = (short)bf16bits(b.w);
    }
    {
        const float4 a = src[2], b = src[3];
        ssq += a.x * a.x + a.y * a.y + a.z * a.z + a.w * a.w
             + b.x * b.x + b.y * b.y + b.z * b.z + b.w * b.w;
        pk1[0] = (short)bf16bits(a.x); pk1[1] = (short)bf16bits(a.y);
        pk1[2] = (short)bf16bits(a.z); pk1[3] = (short)bf16bits(a.w);
        pk1[4] = (short)bf16bits(b.x); pk1[5] = (short)bf16bits(b.y);
        pk1[6] = (short)bf16bits(b.z); pk1[7] = (short)bf16bits(b.w);
    }
    const int nt = e >> 4;
    const int c  = e & 15;
    const int kc0 = 2 * q;        // chunks 2q, 2q+1
    const int idx0 = nt * 128 + (kc0 >> 2) * 64 + (kc0 & 3) * 16 + c;
    const int idx1 = nt * 128 + ((kc0 + 1) >> 2) * 64 + ((kc0 + 1) & 3) * 16 + c;
    ((bf16x8*)cbw)[idx0] = pk0;
    ((bf16x8*)cbw)[idx1] = pk1;
    ssq += __shfl_xor(ssq, 1, 64);
    ssq += __shfl_xor(ssq, 2, 64);
    if (q == 0) ncbn[e] = -0.5f * ssq;
}

// ---------------- main: split-N wave pairs + dense fragment-order B ----------------
// 512 blocks x 256 thr. Wave w: rows (w&1)*64..+63 (4 M-tiles),
// entries (w>>1)*512..+511 (32 n-tiles). Per-wave B = 64 KB (half of R6),
// and every B-load is dense 1 KB. Cross-half argmax merged in LDS.
__launch_bounds__(256, 2)
__global__ void vq_main_kernel(const float* __restrict__ z,
                               const short* __restrict__ cbw,
                               const float* __restrict__ ncbn,
                               const float* __restrict__ cb,
                               float* __restrict__ out,
                               float* __restrict__ pbuf) {
    __shared__ __align__(16) short zt[ROWS * 64];  // 16 KB, swizzled
    __shared__ float ncbn_s[NE];                   // 4 KB
    __shared__ float smax2[2][ROWS];               // per-half row winners
    __shared__ int   sidx2[2][ROWS];
    __shared__ int   rowi[ROWS];
    __shared__ float swsum[4];

    const int tid  = threadIdx.x;
    const int wave = tid >> 6;
    const int lane = tid & 63;
    const int bid  = blockIdx.x;

    ((float4*)ncbn_s)[tid] = ((const float4*)ncbn)[tid];

    // ---- stage z tile: thread -> row (tid&127), channel half (tid>>7) ----
    const int r     = tid & 127;
    const int chalf = tid >> 7;
    const int P     = bid * ROWS + r;
    const int b     = P >> 12;
    const int rem   = P & 4095;
    const size_t zb = ((size_t)b << 18) + rem;
    #pragma unroll
    for (int q = 0; q < 4; ++q) {
        bf16x8 pk;
        #pragma unroll
        for (int jj = 0; jj < 8; ++jj) {
            const int c = chalf * 32 + q * 8 + jj;
            pk[jj] = (short)bf16bits(z[zb + ((size_t)c << 12)]);
        }
        const int boff = (chalf * 32 + q * 8) * 2;
        *(bf16x8*)((char*)zt + r * 128 + swz(r, boff)) = pk;
    }
    __syncthreads();

    // ---- A fragments: wave w rows (w&1)*64 + m*16 + (lane&15) ----
    bf16x8 af[4][2];
    #pragma unroll
    for (int m = 0; m < 4; ++m) {
        const int rr = (wave & 1) * 64 + m * 16 + (lane & 15);
        af[m][0] = *(const bf16x8*)((const char*)zt + rr * 128 + swz(rr, 0  + (lane >> 4) * 16));
        af[m][1] = *(const bf16x8*)((const char*)zt + rr * 128 + swz(rr, 64 + (lane >> 4) * 16));
    }

    float maxv[4][4];
    int   maxi[4][4];
    #pragma unroll
    for (int m = 0; m < 4; ++m)
        #pragma unroll
        for (int j = 0; j < 4; ++j) { maxv[m][j] = -INFINITY; maxi[m][j] = 0; }

    // ---- sweep this wave's 512 entries: 32 n-tiles, dense B loads ----
    const int nhalf = wave >> 1;
    const char* __restrict__ bptr =
        (const char*)cbw + (size_t)nhalf * 32 * 2048 + lane * 16;
    const int c15 = lane & 15;
    #pragma unroll 4
    for (int ntl = 0; ntl < 32; ++ntl) {
        const bf16x8 b0 = *(const bf16x8*)(bptr + ntl * 2048);
        const bf16x8 b1 = *(const bf16x8*)(bptr + ntl * 2048 + 1024);
        const int el    = (nhalf * 32 + ntl) * 16 + c15;   // global entry
        const float ncb = ncbn_s[el];
        #pragma unroll
        for (int m = 0; m < 4; ++m) {
            f32x4 acc = {0.f, 0.f, 0.f, 0.f};
            acc = __builtin_amdgcn_mfma_f32_16x16x32_bf16(af[m][0], b0, acc, 0, 0, 0);
            acc = __builtin_amdgcn_mfma_f32_16x16x32_bf16(af[m][1], b1, acc, 0, 0, 0);
            #pragma unroll
            for (int j = 0; j < 4; ++j) {
                const float sc = acc[j] + ncb;
                if (sc > maxv[m][j]) { maxv[m][j] = sc; maxi[m][j] = el; }
            }
        }
    }

    // ---- intra-wave argmax across the 16 cols; store per-half winners ----
    // element (m, j, lane): row = (wave&1)*64 + m*16 + (lane>>4)*4 + j.
    #pragma unroll
    for (int m = 0; m < 4; ++m) {
        #pragma unroll
        for (int j = 0; j < 4; ++j) {
            float v = maxv[m][j];
            int   i = maxi[m][j];
            #pragma unroll
            for (int s = 1; s < 16; s <<= 1) {
                const float ov = __shfl_xor(v, s, 64);
                const int   oi = __shfl_xor(i, s, 64);
                if (ov > v || (ov == v && oi < i)) { v = ov; i = oi; }
            }
            if ((lane & 15) == 0) {
                const int rr = (wave & 1) * 64 + m * 16 + (lane >> 4) * 4 + j;
                smax2[nhalf][rr] = v;
                sidx2[nhalf][rr] = i;
            }
        }
    }
    __syncthreads();

    // ---- merge halves (lo wins ties -> first-index semantics) ----
    if (tid < ROWS) {
        const float lo = smax2[0][tid];
        const float hi = smax2[1][tid];
        rowi[tid] = (hi > lo) ? sidx2[1][tid] : sidx2[0][tid];
    }
    __syncthreads();

    // ---- epilogue: gather fp32 codebook row, store out, loss ----
    float lsum = 0.f;
    {
        const int mi = rowi[r];
        const float4* __restrict__ qrow = (const float4*)(cb + ((size_t)mi << 6));
        #pragma unroll
        for (int q = 0; q < 8; ++q) {
            const float4 q4 = qrow[chalf * 8 + q];
            const int c = chalf * 32 + q * 4;
            const float z0 = z[zb + ((size_t)(c + 0) << 12)];
            const float z1 = z[zb + ((size_t)(c + 1) << 12)];
            const float z2 = z[zb + ((size_t)(c + 2) << 12)];
            const float z3 = z[zb + ((size_t)(c + 3) << 12)];
            out[zb + ((size_t)(c + 0) << 12)] = q4.x;
            out[zb + ((size_t)(c + 1) << 12)] = q4.y;
            out[zb + ((size_t)(c + 2) << 12)] = q4.z;
            out[zb + ((size_t)(c + 3) << 12)] = q4.w;
            const float d0 = q4.x - z0, d1 = q4.y - z1;
            const float d2 = q4.z - z2, d3 = q4.w - z3;
            lsum += d0 * d0 + d1 * d1 + d2 * d2 + d3 * d3;
        }
    }

    #pragma unroll
    for (int off = 32; off > 0; off >>= 1)
        lsum += __shfl_xor(lsum, off, 64);
    if (lane == 0) swsum[wave] = lsum;
    __syncthreads();
    if (tid == 0) {
        pbuf[bid] = (swsum[0] + swsum[1]) + (swsum[2] + swsum[3]);
    }
}

// ---------------- final: reduce 512 partials -> loss ----------------
__global__ void vq_reduce_kernel(const float* __restrict__ pbuf,
                                 float* __restrict__ loss) {
    __shared__ float sw[8];
    const int tid = threadIdx.x;  // 512
    float v = pbuf[tid];
    #pragma unroll
    for (int off = 32; off > 0; off >>= 1)
        v += __shfl_xor(v, off, 64);
    if ((tid & 63) == 0) sw[tid >> 6] = v;
    __syncthreads();
    if (tid == 0) {
        float s = 0.f;
        #pragma unroll
        for (int i = 0; i < 8; ++i) s += sw[i];
        loss[0] = s * (1.25f / (float)NTOT);
    }
}

extern "C" void kernel_launch(void* const* d_in, const int* in_sizes, int n_in,
                              void* d_out, int out_size, void* d_ws, size_t ws_size,
                              hipStream_t stream) {
    const float* z  = (const float*)d_in[0];
    const float* cb = (const float*)d_in[1];
    float* out  = (float*)d_out;
    float* loss = out + (out_size - 1);

    short* cbw  = (short*)d_ws;                        // [1024][64] bf16, fragment order (128 KB)
    float* ncbn = (float*)(cbw + NE * NC);             // [1024] f32 (4 KB)
    float* pbuf = ncbn + NE;                           // [512] f32 partials (2 KB)

    vq_prep_kernel<<<dim3(16), dim3(256), 0, stream>>>(cb, cbw, ncbn);
    vq_main_kernel<<<dim3(NBLK), dim3(256), 0, stream>>>(z, cbw, ncbn, cb, out, pbuf);
    vq_reduce_kernel<<<dim3(1), dim3(512), 0, stream>>>(pbuf, loss);
}

// Round 10
// 94.993 us; speedup vs baseline: 2.7275x; 1.0531x over previous
//
#include <hip/hip_runtime.h>
#include <math.h>

// z (16,64,64,64) f32 (b,c,h,w), codebook (1024,64) f32. Out: z_q + loss.
#define NB 16
#define NC 64
#define NH 64
#define NW 64
#define NE 1024
#define HW (NH * NW)              // 4096 = 1<<12
#define NTOT (NB * NC * NH * NW)  // 4194304
#define NPIX (NB * NH * NW)       // 65536 pixels (rows)

#define ROWS 128                  // pixels per block
#define NBLK (NPIX / ROWS)        // 512 blocks

typedef short bf16x8 __attribute__((ext_vector_type(8)));
typedef float f32x4  __attribute__((ext_vector_type(4)));

// XOR swizzle within a 128-byte row (A-tile LDS only).
__device__ __forceinline__ int swz(int row, int byteoff) {
    return (byteoff ^ ((row & 7) << 4));
}

// fp32 -> bf16 bits, round-to-nearest-even.
__device__ __forceinline__ unsigned short bf16bits(float f) {
    union { float f; unsigned u; } cv;
    cv.f = f;
    const unsigned u = cv.u;
    return (unsigned short)((u + 0x7FFFu + ((u >> 16) & 1u)) >> 16);
}

// ---------------- prep: FRAGMENT-ORDER bf16 codebook + (-0.5||e||^2) ----------------
// cbw layout (16-B units): idx = nt*128 + half*64 + kgrp*16 + col
//   entry e = nt*16 + col; k-chunk = half*4 + kgrp (8 bf16 each).
// Main-loop lane l loads b0/b1 at base + l*16: 64 lanes unit-stride 1 KB.
__global__ void vq_prep_kernel(const float* __restrict__ cb,
                               short* __restrict__ cbw,
                               float* __restrict__ ncbn) {
    const int gid = blockIdx.x * blockDim.x + threadIdx.x;  // 0..4095
    const int e   = gid >> 2;
    const int q   = gid & 3;      // 16-channel quarter: k = q*16 .. q*16+15
    const float4* __restrict__ src = (const float4*)(cb + ((size_t)e << 6) + q * 16);
    float ssq = 0.f;
    bf16x8 pk0, pk1;
    {
        const float4 a = src[0], b = src[1];
        ssq += a.x * a.x + a.y * a.y + a.z * a.z + a.w * a.w
             + b.x * b.x + b.y * b.y + b.z * b.z + b.w * b.w;
        pk0[0] = (short)bf16bits(a.x); pk0[1] = (short)bf16bits(a.y);
        pk0[2] = (short)bf16bits(a.z); pk0[3] = (short)bf16bits(a.w);
        pk0[4] = (short)bf16bits(b.x); pk0[5] = (short)bf16bits(b.y);
        pk0[6] = (short)bf16bits(b.z); pk0[7] = (short)bf16bits(b.w);
    }
    {
        const float4 a = src[2], b = src[3];
        ssq += a.x * a.x + a.y * a.y + a.z * a.z + a.w * a.w
             + b.x * b.x + b.y * b.y + b.z * b.z + b.w * b.w;
        pk1[0] = (short)bf16bits(a.x); pk1[1] = (short)bf16bits(a.y);
        pk1[2] = (short)bf16bits(a.z); pk1[3] = (short)bf16bits(a.w);
        pk1[4] = (short)bf16bits(b.x); pk1[5] = (short)bf16bits(b.y);
        pk1[6] = (short)bf16bits(b.z); pk1[7] = (short)bf16bits(b.w);
    }
    const int nt = e >> 4;
    const int c  = e & 15;
    const int kc0 = 2 * q;        // chunks 2q, 2q+1
    const int idx0 = nt * 128 + (kc0 >> 2) * 64 + (kc0 & 3) * 16 + c;
    const int idx1 = nt * 128 + ((kc0 + 1) >> 2) * 64 + ((kc0 + 1) & 3) * 16 + c;
    ((bf16x8*)cbw)[idx0] = pk0;
    ((bf16x8*)cbw)[idx1] = pk1;
    ssq += __shfl_xor(ssq, 1, 64);
    ssq += __shfl_xor(ssq, 2, 64);
    if (q == 0) ncbn[e] = -0.5f * ssq;
}

// ---------------- main: 8 waves/block (4 waves/SIMD), 4-way split-N ----------------
// 512 blocks x 512 thr. Wave w: rows (w&1)*64..+63 (4 M-tiles),
// entries (w>>1)*256..+255 (16 n-tiles, dense 32 KB/wave).
// Total B-traffic identical to R9 (128 MB); waves/SIMD doubled (latency test).
__launch_bounds__(512, 4)
__global__ void vq_main_kernel(const float* __restrict__ z,
                               const short* __restrict__ cbw,
                               const float* __restrict__ ncbn,
                               const float* __restrict__ cb,
                               float* __restrict__ out,
                               float* __restrict__ pbuf) {
    __shared__ __align__(16) short zt[ROWS * 64];  // 16 KB, swizzled
    __shared__ float ncbn_s[NE];                   // 4 KB
    __shared__ float smax4[4][ROWS];               // per-quarter row winners
    __shared__ int   sidx4[4][ROWS];
    __shared__ int   rowi[ROWS];
    __shared__ float swsum[8];

    const int tid  = threadIdx.x;
    const int wave = tid >> 6;
    const int lane = tid & 63;
    const int bid  = blockIdx.x;

    // stage ncbn (1024 floats) via 512 x float2
    ((float2*)ncbn_s)[tid] = ((const float2*)ncbn)[tid];

    // ---- stage z tile: thread -> row (tid&127), channel quarter (tid>>7) ----
    const int r   = tid & 127;
    const int cq  = tid >> 7;                 // 16 channels: cq*16 .. cq*16+15
    const int P   = bid * ROWS + r;
    const int b   = P >> 12;
    const int rem = P & 4095;
    const size_t zb = ((size_t)b << 18) + rem;
    #pragma unroll
    for (int q = 0; q < 2; ++q) {
        bf16x8 pk;
        #pragma unroll
        for (int jj = 0; jj < 8; ++jj) {
            const int c = cq * 16 + q * 8 + jj;
            pk[jj] = (short)bf16bits(z[zb + ((size_t)c << 12)]);
        }
        const int boff = (cq * 16 + q * 8) * 2;
        *(bf16x8*)((char*)zt + r * 128 + swz(r, boff)) = pk;
    }
    __syncthreads();

    // ---- A fragments: wave w rows (w&1)*64 + m*16 + (lane&15) ----
    bf16x8 af[4][2];
    #pragma unroll
    for (int m = 0; m < 4; ++m) {
        const int rr = (wave & 1) * 64 + m * 16 + (lane & 15);
        af[m][0] = *(const bf16x8*)((const char*)zt + rr * 128 + swz(rr, 0  + (lane >> 4) * 16));
        af[m][1] = *(const bf16x8*)((const char*)zt + rr * 128 + swz(rr, 64 + (lane >> 4) * 16));
    }

    float maxv[4][4];
    int   maxi[4][4];
    #pragma unroll
    for (int m = 0; m < 4; ++m)
        #pragma unroll
        for (int j = 0; j < 4; ++j) { maxv[m][j] = -INFINITY; maxi[m][j] = 0; }

    // ---- sweep this wave's 256 entries: 16 n-tiles, dense 1 KB loads ----
    const int nq = wave >> 1;                      // entry quarter 0..3
    const char* __restrict__ bptr =
        (const char*)cbw + (size_t)nq * 16 * 2048 + lane * 16;
    const int c15 = lane & 15;
    #pragma unroll 4
    for (int ntl = 0; ntl < 16; ++ntl) {
        const bf16x8 b0 = *(const bf16x8*)(bptr + ntl * 2048);
        const bf16x8 b1 = *(const bf16x8*)(bptr + ntl * 2048 + 1024);
        const int el    = (nq * 16 + ntl) * 16 + c15;   // global entry
        const float ncb = ncbn_s[el];
        #pragma unroll
        for (int m = 0; m < 4; ++m) {
            f32x4 acc = {0.f, 0.f, 0.f, 0.f};
            acc = __builtin_amdgcn_mfma_f32_16x16x32_bf16(af[m][0], b0, acc, 0, 0, 0);
            acc = __builtin_amdgcn_mfma_f32_16x16x32_bf16(af[m][1], b1, acc, 0, 0, 0);
            #pragma unroll
            for (int j = 0; j < 4; ++j) {
                const float sc = acc[j] + ncb;
                if (sc > maxv[m][j]) { maxv[m][j] = sc; maxi[m][j] = el; }
            }
        }
    }

    // ---- intra-wave argmax across the 16 cols; store per-quarter winners ----
    // element (m, j, lane): row = (wave&1)*64 + m*16 + (lane>>4)*4 + j.
    #pragma unroll
    for (int m = 0; m < 4; ++m) {
        #pragma unroll
        for (int j = 0; j < 4; ++j) {
            float v = maxv[m][j];
            int   i = maxi[m][j];
            #pragma unroll
            for (int s = 1; s < 16; s <<= 1) {
                const float ov = __shfl_xor(v, s, 64);
                const int   oi = __shfl_xor(i, s, 64);
                if (ov > v || (ov == v && oi < i)) { v = ov; i = oi; }
            }
            if ((lane & 15) == 0) {
                const int rr = (wave & 1) * 64 + m * 16 + (lane >> 4) * 4 + j;
                smax4[nq][rr] = v;
                sidx4[nq][rr] = i;
            }
        }
    }
    __syncthreads();

    // ---- merge quarters (ascending entry ranges; strict > keeps first idx) ----
    if (tid < ROWS) {
        float v = smax4[0][tid];
        int   i = sidx4[0][tid];
        #pragma unroll
        for (int qq = 1; qq < 4; ++qq) {
            const float ov = smax4[qq][tid];
            if (ov > v) { v = ov; i = sidx4[qq][tid]; }
        }
        rowi[tid] = i;
    }
    __syncthreads();

    // ---- epilogue: gather fp32 codebook row, store out, loss ----
    float lsum = 0.f;
    {
        const int mi = rowi[r];
        const float4* __restrict__ qrow = (const float4*)(cb + ((size_t)mi << 6) + cq * 16);
        #pragma unroll
        for (int q = 0; q < 4; ++q) {
            const float4 q4 = qrow[q];
            const int c = cq * 16 + q * 4;
            const float z0 = z[zb + ((size_t)(c + 0) << 12)];
            const float z1 = z[zb + ((size_t)(c + 1) << 12)];
            const float z2 = z[zb + ((size_t)(c + 2) << 12)];
            const float z3 = z[zb + ((size_t)(c + 3) << 12)];
            out[zb + ((size_t)(c + 0) << 12)] = q4.x;
            out[zb + ((size_t)(c + 1) << 12)] = q4.y;
            out[zb + ((size_t)(c + 2) << 12)] = q4.z;
            out[zb + ((size_t)(c + 3) << 12)] = q4.w;
            const float d0 = q4.x - z0, d1 = q4.y - z1;
            const float d2 = q4.z - z2, d3 = q4.w - z3;
            lsum += d0 * d0 + d1 * d1 + d2 * d2 + d3 * d3;
        }
    }

    #pragma unroll
    for (int off = 32; off > 0; off >>= 1)
        lsum += __shfl_xor(lsum, off, 64);
    if (lane == 0) swsum[wave] = lsum;
    __syncthreads();
    if (tid == 0) {
        float s = 0.f;
        #pragma unroll
        for (int i = 0; i < 8; ++i) s += swsum[i];
        pbuf[bid] = s;
    }
}

// ---------------- final: reduce 512 partials -> loss ----------------
__global__ void vq_reduce_kernel(const float* __restrict__ pbuf,
                                 float* __restrict__ loss) {
    __shared__ float sw[8];
    const int tid = threadIdx.x;  // 512
    float v = pbuf[tid];
    #pragma unroll
    for (int off = 32; off > 0; off >>= 1)
        v += __shfl_xor(v, off, 64);
    if ((tid & 63) == 0) sw[tid >> 6] = v;
    __syncthreads();
    if (tid == 0) {
        float s = 0.f;
        #pragma unroll
        for (int i = 0; i < 8; ++i) s += sw[i];
        loss[0] = s * (1.25f / (float)NTOT);
    }
}

extern "C" void kernel_launch(void* const* d_in, const int* in_sizes, int n_in,
                              void* d_out, int out_size, void* d_ws, size_t ws_size,
                              hipStream_t stream) {
    const float* z  = (const float*)d_in[0];
    const float* cb = (const float*)d_in[1];
    float* out  = (float*)d_out;
    float* loss = out + (out_size - 1);

    short* cbw  = (short*)d_ws;                        // [1024][64] bf16, fragment order (128 KB)
    float* ncbn = (float*)(cbw + NE * NC);             // [1024] f32 (4 KB)
    float* pbuf = ncbn + NE;                           // [512] f32 partials (2 KB)

    vq_prep_kernel<<<dim3(16), dim3(256), 0, stream>>>(cb, cbw, ncbn);
    vq_main_kernel<<<dim3(NBLK), dim3(512), 0, stream>>>(z, cbw, ncbn, cb, out, pbuf);
    vq_reduce_kernel<<<dim3(1), dim3(512), 0, stream>>>(pbuf, loss);
}